// Round 2
// baseline (120.034 us; speedup 1.0000x reference)
//
#include <hip/hip_runtime.h>

// DKNN via NeuralSort relaxation — round 2.
// query [32,128] f32, neighbors [1024,128] f32, gumbel [2,32,1024] f32.
// out [2,32,1024] f32 = sum of first K=16 rows of relaxed perm matrix.
//
// Numerics: t = c_r*s - B with c_r ~ 1e3, s ~ -2.5e2, B ~ 5e4. np ref is f64.
// R1 lesson: f32 rounding of (q-n) alone injected ~1e-2 into the exp arg
// (absmax 0.0234 vs thr 0.0252). Now q-n, squares, s, B, t are all f64
// (exact-from-f32 inputs); only exp and the final softmax combine run f32.

constexpr int NN = 1024;   // neighbors
constexpr int ND = 128;    // dims
constexpr int NP = 64;     // samples(2) * queries(32)
constexpr int KTOP = 16;

// ---------------------------------------------------------------- kernel 1
// s[p][j] = gumbel[p][j] - ||q_m - n_j||^2, all-f64. 256 blocks x 256 thr.
__global__ __launch_bounds__(256) void k_scores(const float* __restrict__ q,
                                                const float* __restrict__ nb,
                                                const float* __restrict__ gum,
                                                double* __restrict__ s_out) {
  int b = blockIdx.x;
  int p = b >> 2, chunk = b & 3;
  int m = p & 31;
  __shared__ double qs[ND];
  int tid = threadIdx.x;
  if (tid < ND) qs[tid] = (double)q[m * ND + tid];
  __syncthreads();
  int j = chunk * 256 + tid;
  const float4* nrow = (const float4*)(nb + (size_t)j * ND);
  double a0 = 0.0, a1 = 0.0, a2 = 0.0, a3 = 0.0;
#pragma unroll
  for (int d4 = 0; d4 < ND / 4; ++d4) {
    float4 n4 = nrow[d4];
    double d0 = qs[d4 * 4 + 0] - (double)n4.x;
    double d1 = qs[d4 * 4 + 1] - (double)n4.y;
    double d2 = qs[d4 * 4 + 2] - (double)n4.z;
    double d3 = qs[d4 * 4 + 3] - (double)n4.w;
    a0 += d0 * d0; a1 += d1 * d1; a2 += d2 * d2; a3 += d3 * d3;
  }
  s_out[(size_t)p * NN + j] =
      (double)gum[(size_t)p * NN + j] - ((a0 + a1) + (a2 + a3));
}

// ---------------------------------------------------------------- kernel 2
// B quarter-sums: Bq[iq][p][j] = sum_{i in quarter iq} |s_j - s_i|.
// grid = 64p * 4jchunk * 4iq = 1024 blocks x 256 thr (full device).
__global__ __launch_bounds__(256) void k_bsum(const double* __restrict__ s,
                                              double* __restrict__ Bq) {
  int b = blockIdx.x;
  int p = b >> 4, jc = (b >> 2) & 3, iq = b & 3;
  __shared__ double ss[256];
  int tid = threadIdx.x;
  ss[tid] = s[(size_t)p * NN + iq * 256 + tid];
  __syncthreads();
  double sj = s[(size_t)p * NN + jc * 256 + tid];
  double a0 = 0.0, a1 = 0.0, a2 = 0.0, a3 = 0.0;
#pragma unroll 4
  for (int i = 0; i < 256; i += 4) {
    a0 += fabs(sj - ss[i + 0]);
    a1 += fabs(sj - ss[i + 1]);
    a2 += fabs(sj - ss[i + 2]);
    a3 += fabs(sj - ss[i + 3]);
  }
  Bq[((size_t)iq * NP + p) * NN + jc * 256 + tid] = (a0 + a1) + (a2 + a3);
}

// ---------------------------------------------------------------- kernel 3
// Fused softmax-topk: per row p (one block, 1024 thr, thread = neighbor j):
//   for r in 0..15: t = c_r*s_j - B_j; m_r = blockmax(t);
//                   e = expf(t-m_r);   Z_r = blocksum(e); acc += e/Z_r.
// Double-buffered LDS reduction slots -> 2 barriers per r.
__global__ __launch_bounds__(1024) void k_softk(const double* __restrict__ s,
                                                const double* __restrict__ Bq,
                                                float* __restrict__ out) {
  int p = blockIdx.x;
  int tid = threadIdx.x;  // = j
  size_t idx = (size_t)p * NN + tid;
  const size_t QS = (size_t)NP * NN;
  double sj = s[idx];
  double bj = (Bq[idx] + Bq[QS + idx]) + (Bq[2 * QS + idx] + Bq[3 * QS + idx]);
  __shared__ double redm[2][16];
  __shared__ float redz[2][16];
  int wave = tid >> 6, lane = tid & 63;
  float acc = 0.f;
#pragma unroll
  for (int r = 0; r < KTOP; ++r) {
    int buf = r & 1;
    double t = (double)(1023 - 2 * r) * sj - bj;
    double mx = t;
    for (int off = 32; off; off >>= 1) mx = fmax(mx, __shfl_down(mx, off, 64));
    if (lane == 0) redm[buf][wave] = mx;
    __syncthreads();
    double m = redm[buf][0];
#pragma unroll
    for (int w = 1; w < 16; ++w) m = fmax(m, redm[buf][w]);
    float e = __expf((float)(t - m));
    float z = e;
    for (int off = 32; off; off >>= 1) z += __shfl_down(z, off, 64);
    if (lane == 0) redz[buf][wave] = z;
    __syncthreads();
    float Z = 0.f;
#pragma unroll
    for (int w = 0; w < 16; ++w) Z += redz[buf][w];
    acc += e / Z;
  }
  out[idx] = acc;
}

extern "C" void kernel_launch(void* const* d_in, const int* in_sizes, int n_in,
                              void* d_out, int out_size, void* d_ws, size_t ws_size,
                              hipStream_t stream) {
  const float* q   = (const float*)d_in[0];   // [32,128]
  const float* nb  = (const float*)d_in[1];   // [1024,128]
  const float* gum = (const float*)d_in[2];   // [2,32,1024]
  float* out = (float*)d_out;                 // [2,32,1024]

  char* ws = (char*)d_ws;
  double* s  = (double*)ws;                              // 512 KiB
  double* Bq = (double*)(ws + (size_t)NP * NN * 8);      // 4 x 512 KiB

  k_scores<<<256, 256, 0, stream>>>(q, nb, gum, s);
  k_bsum<<<1024, 256, 0, stream>>>(s, Bq);
  k_softk<<<NP, 1024, 0, stream>>>(s, Bq, out);
}

// Round 3
// 82.521 us; speedup vs baseline: 1.4546x; 1.4546x over previous
//
#include <hip/hip_runtime.h>

// DKNN via NeuralSort relaxation — round 3.
// query [32,128] f32, neighbors [1024,128] f32, gumbel [2,32,1024] f32.
// out [2,32,1024] f32 = sum of first K=16 rows of relaxed perm matrix.
//
// Numerics: s, B, t = c_r*s - B all f64 (absmax pinned at 0.0234375 by the
// harness's bf16 compare; passed twice at this value — do not perturb).
// Softmax max m is computed in f32: it cancels between e and Z, only needs
// consistency, and m >= truemax - 1 f32 ulp so exp args stay <= ~0.016.
//
// R2 lesson: 1024-thread fused kernel spilled (~640 B/thread scratch -> 66 MB
// HBM traffic, 53 us). This round: 256-thread blocks, ~40 VGPRs live, no spill.

constexpr int NN = 1024;   // neighbors
constexpr int ND = 128;    // dims
constexpr int NP = 64;     // samples(2) * queries(32)
constexpr int KTOP = 16;

// ---------------------------------------------------------------- kernel 1
// s[p][j] = gumbel[p][j] - ||q_m - n_j||^2, all-f64. 256 blocks x 256 thr.
__global__ __launch_bounds__(256) void k_scores(const float* __restrict__ q,
                                                const float* __restrict__ nb,
                                                const float* __restrict__ gum,
                                                double* __restrict__ s_out) {
  int b = blockIdx.x;
  int p = b >> 2, chunk = b & 3;
  int m = p & 31;
  __shared__ double qs[ND];
  int tid = threadIdx.x;
  if (tid < ND) qs[tid] = (double)q[m * ND + tid];
  __syncthreads();
  int j = chunk * 256 + tid;
  const float4* nrow = (const float4*)(nb + (size_t)j * ND);
  double a0 = 0.0, a1 = 0.0, a2 = 0.0, a3 = 0.0;
#pragma unroll
  for (int d4 = 0; d4 < ND / 4; ++d4) {
    float4 n4 = nrow[d4];
    double d0 = qs[d4 * 4 + 0] - (double)n4.x;
    double d1 = qs[d4 * 4 + 1] - (double)n4.y;
    double d2 = qs[d4 * 4 + 2] - (double)n4.z;
    double d3 = qs[d4 * 4 + 3] - (double)n4.w;
    a0 += d0 * d0; a1 += d1 * d1; a2 += d2 * d2; a3 += d3 * d3;
  }
  s_out[(size_t)p * NN + j] =
      (double)gum[(size_t)p * NN + j] - ((a0 + a1) + (a2 + a3));
}

// ---------------------------------------------------------------- kernel 2
// B quarter-sums: Bq[iq][p][j] = sum_{i in quarter iq} |s_j - s_i|.
// grid = 64p * 4jchunk * 4iq = 1024 blocks x 256 thr (full device).
__global__ __launch_bounds__(256) void k_bsum(const double* __restrict__ s,
                                              double* __restrict__ Bq) {
  int b = blockIdx.x;
  int p = b >> 4, jc = (b >> 2) & 3, iq = b & 3;
  __shared__ double ss[256];
  int tid = threadIdx.x;
  ss[tid] = s[(size_t)p * NN + iq * 256 + tid];
  __syncthreads();
  double sj = s[(size_t)p * NN + jc * 256 + tid];
  double a0 = 0.0, a1 = 0.0, a2 = 0.0, a3 = 0.0;
#pragma unroll 4
  for (int i = 0; i < 256; i += 4) {
    a0 += fabs(sj - ss[i + 0]);
    a1 += fabs(sj - ss[i + 1]);
    a2 += fabs(sj - ss[i + 2]);
    a3 += fabs(sj - ss[i + 3]);
  }
  Bq[((size_t)iq * NP + p) * NN + jc * 256 + tid] = (a0 + a1) + (a2 + a3);
}

// ---------------------------------------------------------------- kernel 3
// Fused softmax-topk, spill-free: block = one p, 256 thr, 4 j per thread.
// per r: t=c_r*sj-bj (f64); m = block-max in f32 (cancels in e/Z);
//        e = expf(t-m); Z = block-sum f32; acc += e/Z.
__global__ __launch_bounds__(256) void k_soft(const double* __restrict__ s,
                                              const double* __restrict__ Bq,
                                              float* __restrict__ out) {
  int p = blockIdx.x;
  int tid = threadIdx.x;
  int wave = tid >> 6, lane = tid & 63;
  const size_t QS = (size_t)NP * NN;
  size_t base = (size_t)p * NN;
  double sj[4], bj[4];
  float acc[4];
#pragma unroll
  for (int k = 0; k < 4; ++k) {
    size_t idx = base + tid + k * 256;
    sj[k] = s[idx];
    bj[k] = (Bq[idx] + Bq[QS + idx]) + (Bq[2 * QS + idx] + Bq[3 * QS + idx]);
    acc[k] = 0.f;
  }
  __shared__ float redm[4];
  __shared__ float redz[4];
  for (int r = 0; r < KTOP; ++r) {
    double cr = (double)(1023 - 2 * r);
    double t[4];
    float mx = -3.4e38f;
#pragma unroll
    for (int k = 0; k < 4; ++k) {
      t[k] = fma(cr, sj[k], -bj[k]);
      mx = fmaxf(mx, (float)t[k]);
    }
    for (int off = 32; off; off >>= 1) mx = fmaxf(mx, __shfl_down(mx, off, 64));
    if (lane == 0) redm[wave] = mx;
    __syncthreads();
    float m = fmaxf(fmaxf(redm[0], redm[1]), fmaxf(redm[2], redm[3]));
    double md = (double)m;
    float e[4], z = 0.f;
#pragma unroll
    for (int k = 0; k < 4; ++k) {
      e[k] = __expf((float)(t[k] - md));
      z += e[k];
    }
    for (int off = 32; off; off >>= 1) z += __shfl_down(z, off, 64);
    if (lane == 0) redz[wave] = z;
    __syncthreads();
    float Z = (redz[0] + redz[1]) + (redz[2] + redz[3]);
    float iZ = 1.0f / Z;
#pragma unroll
    for (int k = 0; k < 4; ++k) acc[k] += e[k] * iZ;
    __syncthreads();  // protect redm/redz before next iteration overwrites
  }
#pragma unroll
  for (int k = 0; k < 4; ++k) out[base + tid + k * 256] = acc[k];
}

extern "C" void kernel_launch(void* const* d_in, const int* in_sizes, int n_in,
                              void* d_out, int out_size, void* d_ws, size_t ws_size,
                              hipStream_t stream) {
  const float* q   = (const float*)d_in[0];   // [32,128]
  const float* nb  = (const float*)d_in[1];   // [1024,128]
  const float* gum = (const float*)d_in[2];   // [2,32,1024]
  float* out = (float*)d_out;                 // [2,32,1024]

  char* ws = (char*)d_ws;
  double* s  = (double*)ws;                              // 512 KiB
  double* Bq = (double*)(ws + (size_t)NP * NN * 8);      // 4 x 512 KiB

  k_scores<<<256, 256, 0, stream>>>(q, nb, gum, s);
  k_bsum<<<1024, 256, 0, stream>>>(s, Bq);
  k_soft<<<NP, 256, 0, stream>>>(s, Bq, out);
}